// Round 2
// baseline (7189.993 us; speedup 1.0000x reference)
//
#include <hip/hip_runtime.h>
#include <hip/hip_bf16.h>

typedef __bf16 bf16x8 __attribute__((ext_vector_type(8)));
typedef float f32x4 __attribute__((ext_vector_type(4)));
typedef unsigned long long u64;

#define MFMA16(a, b, c) __builtin_amdgcn_mfma_f32_16x16x32_bf16((a), (b), (c), 0, 0, 0)

#define HN_OFF 8388608ull   // 32*512*512
#define CN_OFF 8421376ull   // HN_OFF + 2*32*512

__device__ __forceinline__ float sigf(float x) { return 1.0f / (1.0f + __expf(-x)); }
__device__ __forceinline__ float b2f(unsigned short u) {
    union { unsigned u; float f; } c; c.u = ((unsigned)u) << 16; return c.f;
}
__device__ __forceinline__ unsigned short f2u(float f) {
    __hip_bfloat16 h = __float2bfloat16(f); return *(unsigned short*)&h;
}

// agent-scope (cross-XCD coherent) accessors
__device__ __forceinline__ u64 gload8(const void* p) {
    return __hip_atomic_load((const u64*)p, __ATOMIC_RELAXED, __HIP_MEMORY_SCOPE_AGENT);
}
__device__ __forceinline__ void gstore8(void* p, u64 v) {
    __hip_atomic_store((u64*)p, v, __ATOMIC_RELAXED, __HIP_MEMORY_SCOPE_AGENT);
}

// split fp32 -> (hi, lo) bf16 pair
__device__ __forceinline__ void split8(const float* p, bf16x8& hi, bf16x8& lo) {
    union { __hip_bfloat16 h[8]; bf16x8 v; } uh, ul;
    #pragma unroll
    for (int i = 0; i < 8; ++i) {
        __hip_bfloat16 e = __float2bfloat16(p[i]);
        uh.h[i] = e;
        ul.h[i] = __float2bfloat16(p[i] - __bfloat162float(e));
    }
    hi = uh.v; lo = ul.v;
}

// ---------------- dtype probe (wave-parallel): 1 = fp32 inputs, 0 = bf16 ----------------
__global__ __launch_bounds__(256) void lstm_detect(
    const unsigned* __restrict__ Wq, unsigned* __restrict__ dflag,
    unsigned* __restrict__ flags)
{
    for (int j = threadIdx.x; j < 1024; j += 256) flags[j] = 0;
    if (threadIdx.x < 64) {
        int lane = threadIdx.x;
        int bad = 0;
        #pragma unroll
        for (int i = 0; i < 4; ++i) {
            unsigned u = Wq[(size_t)(lane + i * 64) * 4093];
            float v = b2f((unsigned short)(u & 0xFFFFu));
            if (!(v == v) || fabsf(v) > 100.0f) ++bad;
        }
        #pragma unroll
        for (int off = 32; off; off >>= 1) bad += __shfl_down(bad, off, 64);
        if (lane == 0) *dflag = (bad > 32) ? 1u : 0u;
    }
}

// ---------------- init: inputs -> packed (hi|lo|tag) words, fp32 c ----------------
// h0 ring slot 0 gets h0[-1] with tag 15 ("step -1"); h1 parity 0 gets h1[-1] tag 0.
__global__ __launch_bounds__(256) void lstm_init(
    const void* __restrict__ h0v, const void* __restrict__ c0v,
    unsigned* __restrict__ h0p, unsigned* __restrict__ h1p,
    float* __restrict__ cws, const unsigned* __restrict__ dflag)
{
    const bool f32 = (*dflag != 0);
    int i = blockIdx.x * 256 + threadIdx.x;   // i = b*512 + n
    int b = i >> 9, n = i & 511;
    float f0, f1, g0, g1;
    if (f32) {
        const float* h = (const float*)h0v; const float* c = (const float*)c0v;
        f0 = h[(b * 2 + 0) * 512 + n];  f1 = h[(b * 2 + 1) * 512 + n];
        g0 = c[(b * 2 + 0) * 512 + n];  g1 = c[(b * 2 + 1) * 512 + n];
    } else {
        const unsigned short* h = (const unsigned short*)h0v;
        const unsigned short* c = (const unsigned short*)c0v;
        f0 = b2f(h[(b * 2 + 0) * 512 + n]);  f1 = b2f(h[(b * 2 + 1) * 512 + n]);
        g0 = b2f(c[(b * 2 + 0) * 512 + n]);  g1 = b2f(c[(b * 2 + 1) * 512 + n]);
    }
    unsigned short h0h = f2u(f0), h1h = f2u(f1);
    unsigned short h0l = f2u(f0 - b2f(h0h)), h1l = f2u(f1 - b2f(h1h));
    h0p[i] = ((unsigned)h0h << 16) | ((unsigned)h0l & 0xFFF0u) | 15u;
    h1p[i] = ((unsigned)h1h << 16) | ((unsigned)h1l & 0xFFF0u) | 0u;
    cws[i] = g0;  cws[16384 + i] = g1;
}

// ---------------- persistent scan: 64 WGs (even=layer0, odd=layer1) ----------------
// Exchange words are self-validating: (hi16<<16)|(lo16&~0xF)|(step&15).
// Consumers gather + spin on tags; no flags/drains on the critical path.
// h0 = 4-slot ring (step k writes slot (k+1)&3, tag k&15); h1 = 2-parity (tag k&15).
// One residual flow-control flag: p1 posts "consumed h0[k-1]" = k; p0 needs >= k-2.
__global__ __launch_bounds__(256, 1) void lstm_seq(
    const void* __restrict__ xv,
    const void* __restrict__ Wxv, const void* __restrict__ bxv,
    const void* __restrict__ Whv, const void* __restrict__ bhv,
    unsigned* __restrict__ h0p, unsigned* __restrict__ h1p,
    const float* __restrict__ cws, unsigned* __restrict__ flags,
    const unsigned* __restrict__ dflag, void* __restrict__ outv)
{
    const bool f32 = (*dflag != 0);
    const int p  = blockIdx.x & 1;
    const int wt = blockIdx.x >> 1;
    const int tid = threadIdx.x;
    const int q = tid >> 6, lane = tid & 63;
    const int n16 = lane & 15, quad = lane >> 4;
    const int colg = q * 512 + wt * 16 + n16;

    __shared__ __align__(16) char smem[131072];
    __shared__ float gbuf[2176];              // [4 gates][32 rows] stride 17

    float* outf = (float*)outv;
    __hip_bfloat16* outh = (__hip_bfloat16*)outv;

    // --- weights -> hi(/lo) bf16 fragments, register-resident for all 512 steps ---
    bf16x8 wa[16], wal[16], wr[16], wrl[16];
    if (f32) {
        const float* WA = (const float*)Wxv + ((size_t)(p * 2048 + colg)) * 512;
        const float* WR = (const float*)Whv + ((size_t)(p * 2048 + colg)) * 512;
        #pragma unroll
        for (int kk = 0; kk < 16; ++kk) {
            split8(WA + kk * 32 + quad * 8, wa[kk], wal[kk]);
            split8(WR + kk * 32 + quad * 8, wr[kk], wrl[kk]);
        }
    } else {
        const unsigned short* WA = (const unsigned short*)Wxv + ((size_t)(p * 2048 + colg)) * 512;
        const unsigned short* WR = (const unsigned short*)Whv + ((size_t)(p * 2048 + colg)) * 512;
        union { uint4 u; bf16x8 v; } cvu;
        #pragma unroll
        for (int kk = 0; kk < 16; ++kk) {
            cvu.u = *(const uint4*)(WA + kk * 32 + quad * 8); wa[kk] = cvu.v;
            cvu.u = *(const uint4*)(WR + kk * 32 + quad * 8); wr[kk] = cvu.v;
        }
    }
    float bias;
    if (f32) bias = ((const float*)bxv)[p * 2048 + colg] + ((const float*)bhv)[p * 2048 + colg];
    else     bias = b2f(((const unsigned short*)bxv)[p * 2048 + colg])
                  + b2f(((const unsigned short*)bhv)[p * 2048 + colg]);

    // pointwise mapping: elems (b, n0), (b, n0+1); fp32 c-state in registers
    const int e0 = tid * 2;
    const int pbb = e0 >> 4;
    const int pn0 = e0 & 15;
    float cv[2];
    cv[0] = cws[p * 16384 + pbb * 512 + wt * 16 + pn0];
    cv[1] = cws[p * 16384 + pbb * 512 + wt * 16 + pn0 + 1];

    const unsigned short* xb = (const unsigned short*)xv;

    #define STAGE_X_BF16(T)                                                      \
        { _Pragma("unroll")                                                      \
          for (int j = 0; j < 8; ++j) {                                          \
              int L = j * 256 + tid;                                             \
              int rem = L & 127;                                                 \
              int row = ((rem >> 6) << 4) + (rem & 15);                          \
              int kcol = ((L >> 7) << 5) + (((rem >> 4) & 3) << 3);              \
              *(uint4*)(smem + (L << 4)) =                                       \
                  *(const uint4*)(xb + ((size_t)row * 512 + (T)) * 512 + kcol);  \
          } }

    #define STAGE_X_F32(T)                                                       \
        { _Pragma("unroll")                                                      \
          for (int j = 0; j < 8; ++j) {                                          \
              int L = j * 256 + tid;                                             \
              int rem = L & 127;                                                 \
              int row = ((rem >> 6) << 4) + (rem & 15);                          \
              int kcol = ((L >> 7) << 5) + (((rem >> 4) & 3) << 3);              \
              const float* xp = (const float*)xv + ((size_t)row * 512 + (T)) * 512 + kcol; \
              bf16x8 hi_, lo_;                                                   \
              split8(xp, hi_, lo_);                                              \
              *(bf16x8*)(smem + (L << 4)) = hi_;                                 \
              *(bf16x8*)(smem + 32768 + (L << 4)) = lo_;                         \
          } }

    // element offset for gather slot s in [0,32): 4 u64 per j-block of 8 elements
    #define EOFF(S_) ({ int L_ = ((S_) >> 2) * 256 + tid; int rem_ = L_ & 127;    \
        int row_ = ((rem_ >> 6) << 4) + (rem_ & 15);                              \
        int kc_  = ((L_ >> 7) << 5) + (((rem_ >> 4) & 3) << 3);                   \
        row_ * 512 + kc_ + ((S_) & 3) * 2; })

    #define GISSUE(SRC)                                                           \
        { _Pragma("unroll")                                                       \
          for (int s_ = 0; s_ < 32; ++s_) V[s_] = gload8((const unsigned*)(SRC) + EOFF(s_)); }

    // spin until every word's 4-bit tag matches WANTV (reload-all policy)
    #define GCHECK(SRC, WANTV)                                                    \
        { const u64 WV_ = (u64)(WANTV) * 0x0000000100000001ULL;                   \
          for (;;) {                                                              \
              u64 d_ = 0;                                                         \
              _Pragma("unroll")                                                   \
              for (int s_ = 0; s_ < 32; ++s_)                                     \
                  d_ |= (V[s_] ^ WV_) & 0x0000000F0000000FULL;                    \
              if (d_ == 0) break;                                                 \
              __builtin_amdgcn_s_sleep(1);                                        \
              _Pragma("unroll")                                                   \
              for (int s_ = 0; s_ < 32; ++s_)                                     \
                  V[s_] = gload8((const unsigned*)(SRC) + EOFF(s_));              \
          } }

    // unpack packed words -> hi tile @DH, lo tile @DL (same layout as MFMA frags)
    #define GSCATTER(DH, DL)                                                      \
        { _Pragma("unroll")                                                       \
          for (int j_ = 0; j_ < 8; ++j_) {                                        \
              union { u64 q; unsigned w[2]; } a_, b_, c_, d_;                     \
              a_.q = V[j_*4+0]; b_.q = V[j_*4+1]; c_.q = V[j_*4+2]; d_.q = V[j_*4+3]; \
              uint4 hi_, lo_;                                                     \
              hi_.x = (a_.w[0] >> 16) | (a_.w[1] & 0xFFFF0000u);                  \
              hi_.y = (b_.w[0] >> 16) | (b_.w[1] & 0xFFFF0000u);                  \
              hi_.z = (c_.w[0] >> 16) | (c_.w[1] & 0xFFFF0000u);                  \
              hi_.w = (d_.w[0] >> 16) | (d_.w[1] & 0xFFFF0000u);                  \
              lo_.x = (a_.w[0] & 0xFFF0u) | ((a_.w[1] & 0xFFF0u) << 16);          \
              lo_.y = (b_.w[0] & 0xFFF0u) | ((b_.w[1] & 0xFFF0u) << 16);          \
              lo_.z = (c_.w[0] & 0xFFF0u) | ((c_.w[1] & 0xFFF0u) << 16);          \
              lo_.w = (d_.w[0] & 0xFFF0u) | ((d_.w[1] & 0xFFF0u) << 16);          \
              int L_ = j_ * 256 + tid;                                            \
              *(uint4*)(smem + (DH) + (L_ << 4)) = hi_;                           \
              *(uint4*)(smem + (DL) + (L_ << 4)) = lo_;                           \
          } }

    // MFMA sub-phases (A tiles @0/32K, R tiles @64K/96K)
    #define MM_A_F32()                                                           \
        { _Pragma("unroll")                                                      \
          for (int kk = 0; kk < 16; ++kk) {                                      \
              bf16x8 Aha = *(const bf16x8*)(sl + kk * 2048);                     \
              bf16x8 Ahb = *(const bf16x8*)(sl + kk * 2048 + 1024);              \
              bf16x8 Ala = *(const bf16x8*)(sl + 32768 + kk * 2048);             \
              bf16x8 Alb = *(const bf16x8*)(sl + 32768 + kk * 2048 + 1024);      \
              acc0 = MFMA16(Aha, wa[kk], acc0);  acc1 = MFMA16(Ahb, wa[kk], acc1);   \
              acc0 = MFMA16(Aha, wal[kk], acc0); acc1 = MFMA16(Ahb, wal[kk], acc1);  \
              acc0 = MFMA16(Ala, wa[kk], acc0);  acc1 = MFMA16(Alb, wa[kk], acc1);   \
          } }

    #define MM_R_F32()                                                           \
        { _Pragma("unroll")                                                      \
          for (int kk = 0; kk < 16; ++kk) {                                      \
              bf16x8 Rha = *(const bf16x8*)(sl + 65536 + kk * 2048);             \
              bf16x8 Rhb = *(const bf16x8*)(sl + 65536 + kk * 2048 + 1024);      \
              bf16x8 Rla = *(const bf16x8*)(sl + 98304 + kk * 2048);             \
              bf16x8 Rlb = *(const bf16x8*)(sl + 98304 + kk * 2048 + 1024);      \
              acc0 = MFMA16(Rha, wr[kk], acc0);  acc1 = MFMA16(Rhb, wr[kk], acc1);   \
              acc0 = MFMA16(Rha, wrl[kk], acc0); acc1 = MFMA16(Rhb, wrl[kk], acc1);  \
              acc0 = MFMA16(Rla, wr[kk], acc0);  acc1 = MFMA16(Rlb, wr[kk], acc1);   \
          } }

    #define MM_A_BF16_P0()                                                       \
        { _Pragma("unroll")                                                      \
          for (int kk = 0; kk < 16; ++kk) {                                      \
              bf16x8 Aha = *(const bf16x8*)(sl + kk * 2048);                     \
              bf16x8 Ahb = *(const bf16x8*)(sl + kk * 2048 + 1024);              \
              acc0 = MFMA16(Aha, wa[kk], acc0);  acc1 = MFMA16(Ahb, wa[kk], acc1);   \
          } }

    #define MM_A_BF16_P1()                                                       \
        { _Pragma("unroll")                                                      \
          for (int kk = 0; kk < 16; ++kk) {                                      \
              bf16x8 Aha = *(const bf16x8*)(sl + kk * 2048);                     \
              bf16x8 Ahb = *(const bf16x8*)(sl + kk * 2048 + 1024);              \
              bf16x8 Ala = *(const bf16x8*)(sl + 32768 + kk * 2048);             \
              bf16x8 Alb = *(const bf16x8*)(sl + 32768 + kk * 2048 + 1024);      \
              acc0 = MFMA16(Aha, wa[kk], acc0);  acc1 = MFMA16(Ahb, wa[kk], acc1);   \
              acc0 = MFMA16(Ala, wa[kk], acc0);  acc1 = MFMA16(Alb, wa[kk], acc1);   \
          } }

    #define MM_R_BF16()                                                          \
        { _Pragma("unroll")                                                      \
          for (int kk = 0; kk < 16; ++kk) {                                      \
              bf16x8 Rha = *(const bf16x8*)(sl + 65536 + kk * 2048);             \
              bf16x8 Rhb = *(const bf16x8*)(sl + 65536 + kk * 2048 + 1024);      \
              bf16x8 Rla = *(const bf16x8*)(sl + 98304 + kk * 2048);             \
              bf16x8 Rlb = *(const bf16x8*)(sl + 98304 + kk * 2048 + 1024);      \
              acc0 = MFMA16(Rha, wr[kk], acc0);  acc1 = MFMA16(Rhb, wr[kk], acc1);   \
              acc0 = MFMA16(Rla, wr[kk], acc0);  acc1 = MFMA16(Rlb, wr[kk], acc1);   \
          } }

    // ---- gate transpose + pointwise epilogue + publish (shared tail) ----
    #define EPILOGUE(ODST, TG)                                                    \
        { _Pragma("unroll")                                                       \
          for (int r = 0; r < 4; ++r) {                                           \
              gbuf[(q * 32 + quad * 4 + r) * 17 + n16]      = acc0[r];            \
              gbuf[(q * 32 + 16 + quad * 4 + r) * 17 + n16] = acc1[r];            \
          } }

    const char* sl = smem + (lane << 4);

    if (p == 0) {
        // =================== layer 0 ===================
        if (f32) { STAGE_X_F32(0) } else { STAGE_X_BF16(0) }
        __syncthreads();

        for (int k = 0; k < 512; ++k) {
            const unsigned want = (unsigned)((k - 1) & 15);
            u64 V[32];
            const unsigned* h0src = h0p + (size_t)(k & 3) * 16384;

            GISSUE(h0src)                         // fresh h0[k-1] in flight
            f32x4 acc0 = {bias, bias, bias, bias};
            f32x4 acc1 = {bias, bias, bias, bias};
            if (f32) { MM_A_F32() } else { MM_A_BF16_P0() }   // x GEMM hides RT
            GCHECK(h0src, want)
            GSCATTER(65536, 98304)
            __syncthreads();
            if (f32) { MM_R_F32() } else { MM_R_BF16() }

            EPILOGUE(,)
            // flow control (off critical path): p1 consumed h0[k-3]?
            if (k >= 3 && tid < 32) {
                while ((int)__hip_atomic_load(&flags[tid * 16],
                           __ATOMIC_RELAXED, __HIP_MEMORY_SCOPE_AGENT) < k - 2)
                    __builtin_amdgcn_s_sleep(2);
            }
            __syncthreads();

            float rh[2], rc[2];
            #pragma unroll
            for (int j = 0; j < 2; ++j) {
                int n = pn0 + j;
                float ig = gbuf[(0 * 32 + pbb) * 17 + n];
                float fg = gbuf[(1 * 32 + pbb) * 17 + n];
                float gg = gbuf[(2 * 32 + pbb) * 17 + n];
                float og = gbuf[(3 * 32 + pbb) * 17 + n];
                float cnew = sigf(fg) * cv[j] + sigf(ig) * tanhf(gg);
                cv[j] = cnew; rc[j] = cnew;
                rh[j] = sigf(og) * tanhf(cnew);
            }
            const unsigned tg = (unsigned)(k & 15);
            unsigned short hu0 = f2u(rh[0]), hu1 = f2u(rh[1]);
            unsigned short lu0 = f2u(rh[0] - b2f(hu0)), lu1 = f2u(rh[1] - b2f(hu1));
            unsigned w0 = ((unsigned)hu0 << 16) | ((unsigned)lu0 & 0xFFF0u) | tg;
            unsigned w1 = ((unsigned)hu1 << 16) | ((unsigned)lu1 & 0xFFF0u) | tg;
            const int idx = pbb * 512 + wt * 16 + pn0;
            gstore8(h0p + (size_t)((k + 1) & 3) * 16384 + idx, ((u64)w1 << 32) | w0);

            if (k == 511) {
                unsigned phi = (unsigned)hu0 | ((unsigned)hu1 << 16);
                unsigned pcn = (unsigned)f2u(rc[0]) | ((unsigned)f2u(rc[1]) << 16);
                if (f32) {
                    outf[HN_OFF + idx] = rh[0]; outf[HN_OFF + idx + 1] = rh[1];
                    outf[CN_OFF + idx] = rc[0]; outf[CN_OFF + idx + 1] = rc[1];
                } else {
                    *(unsigned*)(outh + HN_OFF + idx) = phi;
                    *(unsigned*)(outh + CN_OFF + idx) = pcn;
                }
            }
            if (k + 1 < 512) { if (f32) { STAGE_X_F32(k + 1) } else { STAGE_X_BF16(k + 1) } }
            __syncthreads();
        }
    } else {
        // =================== layer 1 ===================
        for (int k = 1; k <= 512; ++k) {
            const int t = k - 1;
            const unsigned want = (unsigned)((k - 1) & 15);
            u64 V[32];

            // R = h1[k-2] (old, usually ready)
            const unsigned* h1src = h1p + (size_t)((k + 1) & 1) * 16384;
            GISSUE(h1src)
            GCHECK(h1src, want)
            GSCATTER(65536, 98304)
            __syncthreads();

            // A = h0[k-1] (fresh) -- issue, hide under R-GEMM
            const unsigned* h0src = h0p + (size_t)(k & 3) * 16384;
            GISSUE(h0src)
            f32x4 acc0 = {bias, bias, bias, bias};
            f32x4 acc1 = {bias, bias, bias, bias};
            if (f32) { MM_R_F32() } else { MM_R_BF16() }
            GCHECK(h0src, want)
            GSCATTER(0, 32768)
            __syncthreads();
            if (tid == 0)    // consumed h0[k-1] -> p0 may recycle ring
                __hip_atomic_store(&flags[wt * 16], (unsigned)k,
                                   __ATOMIC_RELAXED, __HIP_MEMORY_SCOPE_AGENT);
            if (f32) { MM_A_F32() } else { MM_A_BF16_P1() }

            EPILOGUE(,)
            __syncthreads();

            float rh[2], rc[2];
            #pragma unroll
            for (int j = 0; j < 2; ++j) {
                int n = pn0 + j;
                float ig = gbuf[(0 * 32 + pbb) * 17 + n];
                float fg = gbuf[(1 * 32 + pbb) * 17 + n];
                float gg = gbuf[(2 * 32 + pbb) * 17 + n];
                float og = gbuf[(3 * 32 + pbb) * 17 + n];
                float cnew = sigf(fg) * cv[j] + sigf(ig) * tanhf(gg);
                cv[j] = cnew; rc[j] = cnew;
                rh[j] = sigf(og) * tanhf(cnew);
            }
            const unsigned tg = (unsigned)(k & 15);
            unsigned short hu0 = f2u(rh[0]), hu1 = f2u(rh[1]);
            unsigned short lu0 = f2u(rh[0] - b2f(hu0)), lu1 = f2u(rh[1] - b2f(hu1));
            unsigned w0 = ((unsigned)hu0 << 16) | ((unsigned)lu0 & 0xFFF0u) | tg;
            unsigned w1 = ((unsigned)hu1 << 16) | ((unsigned)lu1 & 0xFFF0u) | tg;
            const int idx = pbb * 512 + wt * 16 + pn0;
            gstore8(h1p + (size_t)(k & 1) * 16384 + idx, ((u64)w1 << 32) | w0);

            unsigned phi = (unsigned)hu0 | ((unsigned)hu1 << 16);
            size_t oidx = ((size_t)pbb * 512 + t) * 512 + wt * 16 + pn0;
            if (f32) { outf[oidx] = rh[0]; outf[oidx + 1] = rh[1]; }
            else     { *(unsigned*)(outh + oidx) = phi; }
            if (k == 512) {
                unsigned pcn = (unsigned)f2u(rc[0]) | ((unsigned)f2u(rc[1]) << 16);
                if (f32) {
                    outf[HN_OFF + 16384 + idx] = rh[0]; outf[HN_OFF + 16385 + idx] = rh[1];
                    outf[CN_OFF + 16384 + idx] = rc[0]; outf[CN_OFF + 16385 + idx] = rc[1];
                } else {
                    *(unsigned*)(outh + HN_OFF + 16384 + idx) = phi;
                    *(unsigned*)(outh + CN_OFF + 16384 + idx) = pcn;
                }
            }
        }
    }
}

extern "C" void kernel_launch(void* const* d_in, const int* in_sizes, int n_in,
                              void* d_out, int out_size, void* d_ws, size_t ws_size,
                              hipStream_t stream)
{
    const void* x  = d_in[0];
    const void* h0 = d_in[1];
    const void* c0 = d_in[2];
    const void* Wx = d_in[3];
    const void* bx = d_in[4];
    const void* Wh = d_in[5];
    const void* bh = d_in[6];

    char* ws = (char*)d_ws;                                    // total need: ~529 KB
    unsigned* h0p  = (unsigned*)(ws);                          // [4][16384] packed ring
    unsigned* h1p  = (unsigned*)(ws + 262144);                 // [2][16384] packed parity
    float*    cws  = (float*)(ws + 393216);                    // [2][16384] f32
    unsigned* flags = (unsigned*)(ws + 524288);                // 32 slots x 16 words
    unsigned* dflag = (unsigned*)(ws + 528384);

    lstm_detect<<<1, 256, 0, stream>>>((const unsigned*)Wx, dflag, flags);
    lstm_init<<<64, 256, 0, stream>>>(h0, c0, h0p, h1p, cws, dflag);
    lstm_seq<<<64, 256, 0, stream>>>(x, Wx, bx, Wh, bh,
                                     h0p, h1p, cws, flags, dflag, d_out);
}

// Round 3
// 6693.380 us; speedup vs baseline: 1.0742x; 1.0742x over previous
//
#include <hip/hip_runtime.h>
#include <hip/hip_bf16.h>

typedef __bf16 bf16x8 __attribute__((ext_vector_type(8)));
typedef float f32x4 __attribute__((ext_vector_type(4)));
typedef unsigned long long u64;

#define MFMA16(a, b, c) __builtin_amdgcn_mfma_f32_16x16x32_bf16((a), (b), (c), 0, 0, 0)

#define HN_OFF 8388608ull   // 32*512*512
#define CN_OFF 8421376ull   // HN_OFF + 2*32*512

__device__ __forceinline__ float sigf(float x) { return 1.0f / (1.0f + __expf(-x)); }
__device__ __forceinline__ float b2f(unsigned short u) {
    union { unsigned u; float f; } c; c.u = ((unsigned)u) << 16; return c.f;
}
__device__ __forceinline__ unsigned short f2u(float f) {
    __hip_bfloat16 h = __float2bfloat16(f); return *(unsigned short*)&h;
}

// agent-scope (cross-XCD coherent) accessors
__device__ __forceinline__ u64 gload8(const void* p) {
    return __hip_atomic_load((const u64*)p, __ATOMIC_RELAXED, __HIP_MEMORY_SCOPE_AGENT);
}
__device__ __forceinline__ void gstore8(void* p, u64 v) {
    __hip_atomic_store((u64*)p, v, __ATOMIC_RELAXED, __HIP_MEMORY_SCOPE_AGENT);
}

// split fp32 -> (hi, lo) bf16 pair
__device__ __forceinline__ void split8(const float* p, bf16x8& hi, bf16x8& lo) {
    union { __hip_bfloat16 h[8]; bf16x8 v; } uh, ul;
    #pragma unroll
    for (int i = 0; i < 8; ++i) {
        __hip_bfloat16 e = __float2bfloat16(p[i]);
        uh.h[i] = e;
        ul.h[i] = __float2bfloat16(p[i] - __bfloat162float(e));
    }
    hi = uh.v; lo = ul.v;
}

// ---------------- dtype probe (wave-parallel): 1 = fp32 inputs, 0 = bf16 ----------------
__global__ __launch_bounds__(256) void lstm_detect(
    const unsigned* __restrict__ Wq, unsigned* __restrict__ dflag,
    unsigned* __restrict__ flags)
{
    for (int j = threadIdx.x; j < 1024; j += 256) flags[j] = 0;
    if (threadIdx.x < 64) {
        int lane = threadIdx.x;
        int bad = 0;
        #pragma unroll
        for (int i = 0; i < 4; ++i) {
            unsigned u = Wq[(size_t)(lane + i * 64) * 4093];
            float v = b2f((unsigned short)(u & 0xFFFFu));
            if (!(v == v) || fabsf(v) > 100.0f) ++bad;
        }
        #pragma unroll
        for (int off = 32; off; off >>= 1) bad += __shfl_down(bad, off, 64);
        if (lane == 0) *dflag = (bad > 32) ? 1u : 0u;
    }
}

// ---------------- init: inputs -> packed (hi|lo|tag) words, fp32 c ----------------
// h0 ring slot 0 gets h0[-1] with tag 15 ("step -1"); h1 parity 0 gets h1[-1] tag 0.
__global__ __launch_bounds__(256) void lstm_init(
    const void* __restrict__ h0v, const void* __restrict__ c0v,
    unsigned* __restrict__ h0p, unsigned* __restrict__ h1p,
    float* __restrict__ cws, const unsigned* __restrict__ dflag)
{
    const bool f32 = (*dflag != 0);
    int i = blockIdx.x * 256 + threadIdx.x;   // i = b*512 + n
    int b = i >> 9, n = i & 511;
    float f0, f1, g0, g1;
    if (f32) {
        const float* h = (const float*)h0v; const float* c = (const float*)c0v;
        f0 = h[(b * 2 + 0) * 512 + n];  f1 = h[(b * 2 + 1) * 512 + n];
        g0 = c[(b * 2 + 0) * 512 + n];  g1 = c[(b * 2 + 1) * 512 + n];
    } else {
        const unsigned short* h = (const unsigned short*)h0v;
        const unsigned short* c = (const unsigned short*)c0v;
        f0 = b2f(h[(b * 2 + 0) * 512 + n]);  f1 = b2f(h[(b * 2 + 1) * 512 + n]);
        g0 = b2f(c[(b * 2 + 0) * 512 + n]);  g1 = b2f(c[(b * 2 + 1) * 512 + n]);
    }
    unsigned short h0h = f2u(f0), h1h = f2u(f1);
    unsigned short h0l = f2u(f0 - b2f(h0h)), h1l = f2u(f1 - b2f(h1h));
    h0p[i] = ((unsigned)h0h << 16) | ((unsigned)h0l & 0xFFF0u) | 15u;
    h1p[i] = ((unsigned)h1h << 16) | ((unsigned)h1l & 0xFFF0u) | 0u;
    cws[i] = g0;  cws[16384 + i] = g1;
}

// ---------------- persistent scan: 64 WGs (even=layer0, odd=layer1) ----------------
// Exchange words self-validating: (hi16<<16)|(lo16&~0xF)|(step&15).
// Rotated loop: store h -> [overlap window: stage/MM_A of next step] -> tagged gather
// (usually hits first try) -> scatter -> MM_R -> epilogue -> store. One RT per step.
// h0 = 4-slot ring (step k -> slot (k+1)&3); h1 = 2-parity (step k -> slot k&1).
// Flow control: p1 posts consumed-h0 counter; p0 requires >= k-2 before ring overwrite.
__global__ __launch_bounds__(256, 1) void lstm_seq(
    const void* __restrict__ xv,
    const void* __restrict__ Wxv, const void* __restrict__ bxv,
    const void* __restrict__ Whv, const void* __restrict__ bhv,
    unsigned* __restrict__ h0p, unsigned* __restrict__ h1p,
    const float* __restrict__ cws, unsigned* __restrict__ flags,
    const unsigned* __restrict__ dflag, void* __restrict__ outv)
{
    const bool f32 = (*dflag != 0);
    const int p  = blockIdx.x & 1;
    const int wt = blockIdx.x >> 1;
    const int tid = threadIdx.x;
    const int q = tid >> 6, lane = tid & 63;
    const int n16 = lane & 15, quad = lane >> 4;
    const int colg = q * 512 + wt * 16 + n16;

    __shared__ __align__(16) char smem[131072];
    __shared__ float gbuf[2176];              // [4 gates][32 rows] stride 17

    float* outf = (float*)outv;
    __hip_bfloat16* outh = (__hip_bfloat16*)outv;

    // --- weights -> hi(/lo) bf16 fragments, register-resident for all 512 steps ---
    bf16x8 wa[16], wal[16], wr[16], wrl[16];
    if (f32) {
        const float* WA = (const float*)Wxv + ((size_t)(p * 2048 + colg)) * 512;
        const float* WR = (const float*)Whv + ((size_t)(p * 2048 + colg)) * 512;
        #pragma unroll
        for (int kk = 0; kk < 16; ++kk) {
            split8(WA + kk * 32 + quad * 8, wa[kk], wal[kk]);
            split8(WR + kk * 32 + quad * 8, wr[kk], wrl[kk]);
        }
    } else {
        const unsigned short* WA = (const unsigned short*)Wxv + ((size_t)(p * 2048 + colg)) * 512;
        const unsigned short* WR = (const unsigned short*)Whv + ((size_t)(p * 2048 + colg)) * 512;
        union { uint4 u; bf16x8 v; } cvu;
        #pragma unroll
        for (int kk = 0; kk < 16; ++kk) {
            cvu.u = *(const uint4*)(WA + kk * 32 + quad * 8); wa[kk] = cvu.v;
            cvu.u = *(const uint4*)(WR + kk * 32 + quad * 8); wr[kk] = cvu.v;
        }
    }
    float bias;
    if (f32) bias = ((const float*)bxv)[p * 2048 + colg] + ((const float*)bhv)[p * 2048 + colg];
    else     bias = b2f(((const unsigned short*)bxv)[p * 2048 + colg])
                  + b2f(((const unsigned short*)bhv)[p * 2048 + colg]);

    // pointwise mapping: elems (b, n0), (b, n0+1); fp32 c-state in registers
    const int e0 = tid * 2;
    const int pbb = e0 >> 4;
    const int pn0 = e0 & 15;
    float cv[2];
    cv[0] = cws[p * 16384 + pbb * 512 + wt * 16 + pn0];
    cv[1] = cws[p * 16384 + pbb * 512 + wt * 16 + pn0 + 1];

    const unsigned short* xb = (const unsigned short*)xv;

    #define STAGE_X_BF16(T)                                                      \
        { _Pragma("unroll")                                                      \
          for (int j = 0; j < 8; ++j) {                                          \
              int L = j * 256 + tid;                                             \
              int rem = L & 127;                                                 \
              int row = ((rem >> 6) << 4) + (rem & 15);                          \
              int kcol = ((L >> 7) << 5) + (((rem >> 4) & 3) << 3);              \
              *(uint4*)(smem + (L << 4)) =                                       \
                  *(const uint4*)(xb + ((size_t)row * 512 + (T)) * 512 + kcol);  \
          } }

    #define STAGE_X_F32(T)                                                       \
        { _Pragma("unroll")                                                      \
          for (int j = 0; j < 8; ++j) {                                          \
              int L = j * 256 + tid;                                             \
              int rem = L & 127;                                                 \
              int row = ((rem >> 6) << 4) + (rem & 15);                          \
              int kcol = ((L >> 7) << 5) + (((rem >> 4) & 3) << 3);              \
              const float* xp = (const float*)xv + ((size_t)row * 512 + (T)) * 512 + kcol; \
              bf16x8 hi_, lo_;                                                   \
              split8(xp, hi_, lo_);                                              \
              *(bf16x8*)(smem + (L << 4)) = hi_;                                 \
              *(bf16x8*)(smem + 32768 + (L << 4)) = lo_;                         \
          } }

    // element offset for gather slot s in [0,32)
    #define EOFF(S_) ({ int L_ = ((S_) >> 2) * 256 + tid; int rem_ = L_ & 127;    \
        int row_ = ((rem_ >> 6) << 4) + (rem_ & 15);                              \
        int kc_  = ((L_ >> 7) << 5) + (((rem_ >> 4) & 3) << 3);                   \
        row_ * 512 + kc_ + ((S_) & 3) * 2; })

    #define GISSUE(SRC)                                                           \
        { _Pragma("unroll")                                                       \
          for (int s_ = 0; s_ < 32; ++s_) V[s_] = gload8((const unsigned*)(SRC) + EOFF(s_)); }

    // spin until every word's 4-bit tag matches; tight first 8 retries, then naps
    #define GCHECK(SRC, WANTV)                                                    \
        { const u64 WV_ = (u64)(WANTV) * 0x0000000100000001ULL;                   \
          int it_ = 0;                                                            \
          for (;;) {                                                              \
              u64 d_ = 0;                                                         \
              _Pragma("unroll")                                                   \
              for (int s_ = 0; s_ < 32; ++s_)                                     \
                  d_ |= (V[s_] ^ WV_) & 0x0000000F0000000FULL;                    \
              if (d_ == 0) break;                                                 \
              if (++it_ > 8) __builtin_amdgcn_s_sleep(1);                         \
              _Pragma("unroll")                                                   \
              for (int s_ = 0; s_ < 32; ++s_)                                     \
                  V[s_] = gload8((const unsigned*)(SRC) + EOFF(s_));              \
          } }

    // unpack packed words -> hi tile @DH, lo tile @DL
    #define GSCATTER(DH, DL)                                                      \
        { _Pragma("unroll")                                                       \
          for (int j_ = 0; j_ < 8; ++j_) {                                        \
              union { u64 q; unsigned w[2]; } a_, b_, c_, d_;                     \
              a_.q = V[j_*4+0]; b_.q = V[j_*4+1]; c_.q = V[j_*4+2]; d_.q = V[j_*4+3]; \
              uint4 hi_, lo_;                                                     \
              hi_.x = (a_.w[0] >> 16) | (a_.w[1] & 0xFFFF0000u);                  \
              hi_.y = (b_.w[0] >> 16) | (b_.w[1] & 0xFFFF0000u);                  \
              hi_.z = (c_.w[0] >> 16) | (c_.w[1] & 0xFFFF0000u);                  \
              hi_.w = (d_.w[0] >> 16) | (d_.w[1] & 0xFFFF0000u);                  \
              lo_.x = (a_.w[0] & 0xFFF0u) | ((a_.w[1] & 0xFFF0u) << 16);          \
              lo_.y = (b_.w[0] & 0xFFF0u) | ((b_.w[1] & 0xFFF0u) << 16);          \
              lo_.z = (c_.w[0] & 0xFFF0u) | ((c_.w[1] & 0xFFF0u) << 16);          \
              lo_.w = (d_.w[0] & 0xFFF0u) | ((d_.w[1] & 0xFFF0u) << 16);          \
              int L_ = j_ * 256 + tid;                                            \
              *(uint4*)(smem + (DH) + (L_ << 4)) = hi_;                           \
              *(uint4*)(smem + (DL) + (L_ << 4)) = lo_;                           \
          } }

    // MFMA sub-phases (A tiles @0/32K, R tiles @64K/96K)
    #define MM_A_F32()                                                           \
        { _Pragma("unroll")                                                      \
          for (int kk = 0; kk < 16; ++kk) {                                      \
              bf16x8 Aha = *(const bf16x8*)(sl + kk * 2048);                     \
              bf16x8 Ahb = *(const bf16x8*)(sl + kk * 2048 + 1024);              \
              bf16x8 Ala = *(const bf16x8*)(sl + 32768 + kk * 2048);             \
              bf16x8 Alb = *(const bf16x8*)(sl + 32768 + kk * 2048 + 1024);      \
              acc0 = MFMA16(Aha, wa[kk], acc0);  acc1 = MFMA16(Ahb, wa[kk], acc1);   \
              acc0 = MFMA16(Aha, wal[kk], acc0); acc1 = MFMA16(Ahb, wal[kk], acc1);  \
              acc0 = MFMA16(Ala, wa[kk], acc0);  acc1 = MFMA16(Alb, wa[kk], acc1);   \
          } }

    #define MM_R_F32()                                                           \
        { _Pragma("unroll")                                                      \
          for (int kk = 0; kk < 16; ++kk) {                                      \
              bf16x8 Rha = *(const bf16x8*)(sl + 65536 + kk * 2048);             \
              bf16x8 Rhb = *(const bf16x8*)(sl + 65536 + kk * 2048 + 1024);      \
              bf16x8 Rla = *(const bf16x8*)(sl + 98304 + kk * 2048);             \
              bf16x8 Rlb = *(const bf16x8*)(sl + 98304 + kk * 2048 + 1024);      \
              acc0 = MFMA16(Rha, wr[kk], acc0);  acc1 = MFMA16(Rhb, wr[kk], acc1);   \
              acc0 = MFMA16(Rha, wrl[kk], acc0); acc1 = MFMA16(Rhb, wrl[kk], acc1);  \
              acc0 = MFMA16(Rla, wr[kk], acc0);  acc1 = MFMA16(Rlb, wr[kk], acc1);   \
          } }

    #define MM_A_BF16_P0()                                                       \
        { _Pragma("unroll")                                                      \
          for (int kk = 0; kk < 16; ++kk) {                                      \
              bf16x8 Aha = *(const bf16x8*)(sl + kk * 2048);                     \
              bf16x8 Ahb = *(const bf16x8*)(sl + kk * 2048 + 1024);              \
              acc0 = MFMA16(Aha, wa[kk], acc0);  acc1 = MFMA16(Ahb, wa[kk], acc1);   \
          } }

    #define MM_A_BF16_P1()                                                       \
        { _Pragma("unroll")                                                      \
          for (int kk = 0; kk < 16; ++kk) {                                      \
              bf16x8 Aha = *(const bf16x8*)(sl + kk * 2048);                     \
              bf16x8 Ahb = *(const bf16x8*)(sl + kk * 2048 + 1024);              \
              bf16x8 Ala = *(const bf16x8*)(sl + 32768 + kk * 2048);             \
              bf16x8 Alb = *(const bf16x8*)(sl + 32768 + kk * 2048 + 1024);      \
              acc0 = MFMA16(Aha, wa[kk], acc0);  acc1 = MFMA16(Ahb, wa[kk], acc1);   \
              acc0 = MFMA16(Ala, wa[kk], acc0);  acc1 = MFMA16(Alb, wa[kk], acc1);   \
          } }

    #define MM_R_BF16()                                                          \
        { _Pragma("unroll")                                                      \
          for (int kk = 0; kk < 16; ++kk) {                                      \
              bf16x8 Rha = *(const bf16x8*)(sl + 65536 + kk * 2048);             \
              bf16x8 Rhb = *(const bf16x8*)(sl + 65536 + kk * 2048 + 1024);      \
              bf16x8 Rla = *(const bf16x8*)(sl + 98304 + kk * 2048);             \
              bf16x8 Rlb = *(const bf16x8*)(sl + 98304 + kk * 2048 + 1024);      \
              acc0 = MFMA16(Rha, wr[kk], acc0);  acc1 = MFMA16(Rhb, wr[kk], acc1);   \
              acc0 = MFMA16(Rla, wr[kk], acc0);  acc1 = MFMA16(Rlb, wr[kk], acc1);   \
          } }

    #define POINTWISE()                                                           \
        float rh[2], rc[2];                                                       \
        { _Pragma("unroll")                                                       \
          for (int j = 0; j < 2; ++j) {                                           \
              int n = pn0 + j;                                                    \
              float ig = gbuf[(0 * 32 + pbb) * 17 + n];                           \
              float fg = gbuf[(1 * 32 + pbb) * 17 + n];                           \
              float gg = gbuf[(2 * 32 + pbb) * 17 + n];                           \
              float og = gbuf[(3 * 32 + pbb) * 17 + n];                           \
              float cnew = sigf(fg) * cv[j] + sigf(ig) * tanhf(gg);               \
              cv[j] = cnew; rc[j] = cnew;                                         \
              rh[j] = sigf(og) * tanhf(cnew);                                     \
          } }

    #define GBUF_WR()                                                             \
        { _Pragma("unroll")                                                       \
          for (int r = 0; r < 4; ++r) {                                           \
              gbuf[(q * 32 + quad * 4 + r) * 17 + n16]      = acc0[r];            \
              gbuf[(q * 32 + 16 + quad * 4 + r) * 17 + n16] = acc1[r];            \
          } }

    const char* sl = smem + (lane << 4);
    const int idx = pbb * 512 + wt * 16 + pn0;
    u64 V[32];
    f32x4 acc0, acc1;

    if (p == 0) {
        // =================== layer 0 ===================
        // prologue: stage x[0], A-GEMM, gather h0[-1] (init, ready)
        if (f32) { STAGE_X_F32(0) } else { STAGE_X_BF16(0) }
        __syncthreads();
        acc0 = (f32x4){bias, bias, bias, bias}; acc1 = acc0;
        if (f32) { MM_A_F32() } else { MM_A_BF16_P0() }
        { const unsigned* s0 = h0p; GISSUE(s0) GCHECK(s0, 15u) }

        for (int k = 0; k < 512; ++k) {
            GSCATTER(65536, 98304)
            __syncthreads();
            if (f32) { MM_R_F32() } else { MM_R_BF16() }
            GBUF_WR()
            __syncthreads();
            POINTWISE()
            const unsigned tg = (unsigned)(k & 15);
            unsigned short hu0 = f2u(rh[0]), hu1 = f2u(rh[1]);
            unsigned short lu0 = f2u(rh[0] - b2f(hu0)), lu1 = f2u(rh[1] - b2f(hu1));
            unsigned w0 = ((unsigned)hu0 << 16) | ((unsigned)lu0 & 0xFFF0u) | tg;
            unsigned w1 = ((unsigned)hu1 << 16) | ((unsigned)lu1 & 0xFFF0u) | tg;

            // flow control before ring overwrite (usually one satisfied load)
            if (k >= 3 && tid < 32) {
                while ((int)__hip_atomic_load(&flags[tid * 16],
                           __ATOMIC_RELAXED, __HIP_MEMORY_SCOPE_AGENT) < k - 2) {}
            }
            gstore8(h0p + (size_t)((k + 1) & 3) * 16384 + idx, ((u64)w1 << 32) | w0);

            if (k == 511) {
                unsigned phi = (unsigned)hu0 | ((unsigned)hu1 << 16);
                unsigned pcn = (unsigned)f2u(rc[0]) | ((unsigned)f2u(rc[1]) << 16);
                if (f32) {
                    outf[HN_OFF + idx] = rh[0]; outf[HN_OFF + idx + 1] = rh[1];
                    outf[CN_OFF + idx] = rc[0]; outf[CN_OFF + idx + 1] = rc[1];
                } else {
                    *(unsigned*)(outh + HN_OFF + idx) = phi;
                    *(unsigned*)(outh + CN_OFF + idx) = pcn;
                }
            } else {
                // overlap window: stage x[k+1] + A-GEMM while h0[k] store propagates
                if (f32) { STAGE_X_F32(k + 1) } else { STAGE_X_BF16(k + 1) }
                __syncthreads();
                acc0 = (f32x4){bias, bias, bias, bias}; acc1 = acc0;
                if (f32) { MM_A_F32() } else { MM_A_BF16_P0() }
                const unsigned* h0src = h0p + (size_t)((k + 1) & 3) * 16384;
                GISSUE(h0src) GCHECK(h0src, tg)
            }
        }
    } else {
        // =================== layer 1 ===================
        // prologue: A = h0[0] (wait p0 step 0), then R = h1[-1] (init, ready)
        { const unsigned* s0 = h0p + 16384; GISSUE(s0) GCHECK(s0, 0u) }
        GSCATTER(0, 32768)
        __syncthreads();
        if (tid == 0)
            __hip_atomic_store(&flags[wt * 16], 1u,
                               __ATOMIC_RELAXED, __HIP_MEMORY_SCOPE_AGENT);
        acc0 = (f32x4){bias, bias, bias, bias}; acc1 = acc0;
        if (f32) { MM_A_F32() } else { MM_A_BF16_P1() }
        { const unsigned* s1 = h1p; GISSUE(s1) GCHECK(s1, 0u) }

        for (int k = 1; k <= 512; ++k) {
            GSCATTER(65536, 98304)
            __syncthreads();
            if (f32) { MM_R_F32() } else { MM_R_BF16() }
            GBUF_WR()
            __syncthreads();
            POINTWISE()
            const unsigned tg = (unsigned)(k & 15);
            unsigned short hu0 = f2u(rh[0]), hu1 = f2u(rh[1]);
            unsigned short lu0 = f2u(rh[0] - b2f(hu0)), lu1 = f2u(rh[1] - b2f(hu1));
            unsigned w0 = ((unsigned)hu0 << 16) | ((unsigned)lu0 & 0xFFF0u) | tg;
            unsigned w1 = ((unsigned)hu1 << 16) | ((unsigned)lu1 & 0xFFF0u) | tg;
            gstore8(h1p + (size_t)(k & 1) * 16384 + idx, ((u64)w1 << 32) | w0);

            unsigned phi = (unsigned)hu0 | ((unsigned)hu1 << 16);
            size_t oidx = ((size_t)pbb * 512 + (k - 1)) * 512 + wt * 16 + pn0;
            if (f32) { outf[oidx] = rh[0]; outf[oidx + 1] = rh[1]; }
            else     { *(unsigned*)(outh + oidx) = phi; }
            if (k == 512) {
                unsigned pcn = (unsigned)f2u(rc[0]) | ((unsigned)f2u(rc[1]) << 16);
                if (f32) {
                    outf[HN_OFF + 16384 + idx] = rh[0]; outf[HN_OFF + 16385 + idx] = rh[1];
                    outf[CN_OFF + 16384 + idx] = rc[0]; outf[CN_OFF + 16385 + idx] = rc[1];
                } else {
                    *(unsigned*)(outh + HN_OFF + 16384 + idx) = phi;
                    *(unsigned*)(outh + CN_OFF + 16384 + idx) = pcn;
                }
                break;
            }

            // overlap window: fetch h0[k] (p0 ahead), A-GEMM; h1[k] store propagates
            {
                const unsigned* h0src = h0p + (size_t)((k + 1) & 3) * 16384;
                GISSUE(h0src) GCHECK(h0src, tg)
            }
            GSCATTER(0, 32768)
            __syncthreads();
            if (tid == 0)   // full WG validated h0[k] -> p0 may recycle its slot
                __hip_atomic_store(&flags[wt * 16], (unsigned)(k + 1),
                                   __ATOMIC_RELAXED, __HIP_MEMORY_SCOPE_AGENT);
            acc0 = (f32x4){bias, bias, bias, bias}; acc1 = acc0;
            if (f32) { MM_A_F32() } else { MM_A_BF16_P1() }
            {
                const unsigned* h1src = h1p + (size_t)(k & 1) * 16384;
                GISSUE(h1src) GCHECK(h1src, tg)
            }
        }
    }
}

extern "C" void kernel_launch(void* const* d_in, const int* in_sizes, int n_in,
                              void* d_out, int out_size, void* d_ws, size_t ws_size,
                              hipStream_t stream)
{
    const void* x  = d_in[0];
    const void* h0 = d_in[1];
    const void* c0 = d_in[2];
    const void* Wx = d_in[3];
    const void* bx = d_in[4];
    const void* Wh = d_in[5];
    const void* bh = d_in[6];

    char* ws = (char*)d_ws;                                    // total need: ~529 KB
    unsigned* h0p  = (unsigned*)(ws);                          // [4][16384] packed ring
    unsigned* h1p  = (unsigned*)(ws + 262144);                 // [2][16384] packed parity
    float*    cws  = (float*)(ws + 393216);                    // [2][16384] f32
    unsigned* flags = (unsigned*)(ws + 524288);                // 32 slots x 16 words
    unsigned* dflag = (unsigned*)(ws + 528384);

    lstm_detect<<<1, 256, 0, stream>>>((const unsigned*)Wx, dflag, flags);
    lstm_init<<<64, 256, 0, stream>>>(h0, c0, h0p, h1p, cws, dflag);
    lstm_seq<<<64, 256, 0, stream>>>(x, Wx, bx, Wh, bh,
                                     h0p, h1p, cws, flags, dflag, d_out);
}

// Round 6
// 6207.121 us; speedup vs baseline: 1.1583x; 1.0783x over previous
//
#include <hip/hip_runtime.h>
#include <hip/hip_bf16.h>

typedef __bf16 bf16x8 __attribute__((ext_vector_type(8)));
typedef float f32x4 __attribute__((ext_vector_type(4)));
typedef unsigned long long u64;

#define MFMA16(a, b, c) __builtin_amdgcn_mfma_f32_16x16x32_bf16((a), (b), (c), 0, 0, 0)

#define HN_OFF 8388608ull   // 32*512*512
#define CN_OFF 8421376ull   // HN_OFF + 2*32*512

__device__ __forceinline__ float sigf(float x) { return 1.0f / (1.0f + __expf(-x)); }
__device__ __forceinline__ float b2f(unsigned short u) {
    union { unsigned u; float f; } c; c.u = ((unsigned)u) << 16; return c.f;
}
__device__ __forceinline__ unsigned short f2u(float f) {
    __hip_bfloat16 h = __float2bfloat16(f); return *(unsigned short*)&h;
}

// agent-scope (cross-XCD coherent) accessors
__device__ __forceinline__ u64 gload8(const void* p) {
    return __hip_atomic_load((const u64*)p, __ATOMIC_RELAXED, __HIP_MEMORY_SCOPE_AGENT);
}
__device__ __forceinline__ void gstore4(void* p, unsigned v) {
    __hip_atomic_store((unsigned*)p, v, __ATOMIC_RELAXED, __HIP_MEMORY_SCOPE_AGENT);
}

// split fp32 -> (hi, lo) bf16 pair
__device__ __forceinline__ void split8(const float* p, bf16x8& hi, bf16x8& lo) {
    union { __hip_bfloat16 h[8]; bf16x8 v; } uh, ul;
    #pragma unroll
    for (int i = 0; i < 8; ++i) {
        __hip_bfloat16 e = __float2bfloat16(p[i]);
        uh.h[i] = e;
        ul.h[i] = __float2bfloat16(p[i] - __bfloat162float(e));
    }
    hi = uh.v; lo = ul.v;
}

// ---------------- dtype probe (wave-parallel): 1 = fp32 inputs, 0 = bf16 ----------------
__global__ __launch_bounds__(256) void lstm_detect(
    const unsigned* __restrict__ Wq, unsigned* __restrict__ dflag,
    unsigned* __restrict__ flags)
{
    for (int j = threadIdx.x; j < 1024; j += 256) flags[j] = 0;
    if (threadIdx.x < 64) {
        int lane = threadIdx.x;
        int bad = 0;
        #pragma unroll
        for (int i = 0; i < 4; ++i) {
            unsigned u = Wq[(size_t)(lane + i * 64) * 4093];
            float v = b2f((unsigned short)(u & 0xFFFFu));
            if (!(v == v) || fabsf(v) > 100.0f) ++bad;
        }
        #pragma unroll
        for (int off = 32; off; off >>= 1) bad += __shfl_down(bad, off, 64);
        if (lane == 0) *dflag = (bad > 32) ? 1u : 0u;
    }
}

// ---------------- init: inputs -> hi/lo state, fp32 c ----------------
// h0 ring slot 0 gets h0[-1]; h1 parity 0 gets h1[-1].
__global__ __launch_bounds__(256) void lstm_init(
    const void* __restrict__ h0v, const void* __restrict__ c0v,
    __hip_bfloat16* __restrict__ h0hi, __hip_bfloat16* __restrict__ h0lo,
    __hip_bfloat16* __restrict__ h1hi, __hip_bfloat16* __restrict__ h1lo,
    float* __restrict__ cws, const unsigned* __restrict__ dflag)
{
    const bool f32 = (*dflag != 0);
    int i = blockIdx.x * 256 + threadIdx.x;   // i = b*512 + n
    int b = i >> 9, n = i & 511;
    float f0, f1, g0, g1;
    if (f32) {
        const float* h = (const float*)h0v; const float* c = (const float*)c0v;
        f0 = h[(b * 2 + 0) * 512 + n];  f1 = h[(b * 2 + 1) * 512 + n];
        g0 = c[(b * 2 + 0) * 512 + n];  g1 = c[(b * 2 + 1) * 512 + n];
    } else {
        const unsigned short* h = (const unsigned short*)h0v;
        const unsigned short* c = (const unsigned short*)c0v;
        f0 = b2f(h[(b * 2 + 0) * 512 + n]);  f1 = b2f(h[(b * 2 + 1) * 512 + n]);
        g0 = b2f(c[(b * 2 + 0) * 512 + n]);  g1 = b2f(c[(b * 2 + 1) * 512 + n]);
    }
    __hip_bfloat16 e0 = __float2bfloat16(f0), e1 = __float2bfloat16(f1);
    h0hi[i] = e0; h0lo[i] = __float2bfloat16(f0 - __bfloat162float(e0));
    h1hi[i] = e1; h1lo[i] = __float2bfloat16(f1 - __bfloat162float(e1));
    cws[i] = g0;  cws[16384 + i] = g1;
}

// ---------------- persistent scan: 64 worker WGs + 192 clock-ballast WGs ----------------
// Workers identical to the 6215us R1 kernel (even=layer0, odd=layer1, decoupled flags,
// h0 4-slot ring / h1 2-parity). Ballast WGs (blockIdx>=64) spin FP32 FMA on the idle
// 192 CUs to hold SCLK at max during the latency-bound sequential phase; they exit when
// flags[8] is set by the first finishing layer-1 WG.
__global__ __launch_bounds__(256, 1) void lstm_seq(
    const void* __restrict__ xv,
    const void* __restrict__ Wxv, const void* __restrict__ bxv,
    const void* __restrict__ Whv, const void* __restrict__ bhv,
    __hip_bfloat16* __restrict__ h0hi, __hip_bfloat16* __restrict__ h0lo,
    __hip_bfloat16* __restrict__ h1hi, __hip_bfloat16* __restrict__ h1lo,
    const float* __restrict__ cws, unsigned* __restrict__ flags,
    const unsigned* __restrict__ dflag, void* __restrict__ outv)
{
    const int tid = threadIdx.x;
    __shared__ unsigned hdone;

    if (blockIdx.x >= 64) {
        // ---- clock ballast: dense FMA until workers finish ----
        float a0 = (float)tid, a1 = a0 + 1.f, a2 = a0 + 2.f, a3 = a0 + 3.f,
              a4 = a0 + 4.f, a5 = a0 + 5.f, a6 = a0 + 6.f, a7 = a0 + 7.f;
        for (;;) {
            for (int it = 0; it < 512; ++it) {
                a0 = __builtin_fmaf(a0, 1.0000001f, 1.0e-7f);
                a1 = __builtin_fmaf(a1, 1.0000001f, 1.1e-7f);
                a2 = __builtin_fmaf(a2, 1.0000001f, 1.2e-7f);
                a3 = __builtin_fmaf(a3, 1.0000001f, 1.3e-7f);
                a4 = __builtin_fmaf(a4, 1.0000001f, 1.4e-7f);
                a5 = __builtin_fmaf(a5, 1.0000001f, 1.5e-7f);
                a6 = __builtin_fmaf(a6, 1.0000001f, 1.6e-7f);
                a7 = __builtin_fmaf(a7, 1.0000001f, 1.7e-7f);
            }
            asm volatile("" :: "v"(a0), "v"(a1), "v"(a2), "v"(a3),
                              "v"(a4), "v"(a5), "v"(a6), "v"(a7));
            if (tid == 0)
                hdone = __hip_atomic_load(&flags[8], __ATOMIC_RELAXED,
                                          __HIP_MEMORY_SCOPE_AGENT);
            __syncthreads();
            unsigned d = hdone;
            __syncthreads();
            if (d) return;
        }
    }

    const bool f32 = (*dflag != 0);
    const int p  = blockIdx.x & 1;
    const int wt = blockIdx.x >> 1;
    const int q = tid >> 6, lane = tid & 63;
    const int n16 = lane & 15, quad = lane >> 4;
    const int colg = q * 512 + wt * 16 + n16;

    __shared__ __align__(16) char smem[131072];
    __shared__ float gbuf[2176];              // [4 gates][32 rows] stride 17

    float* outf = (float*)outv;
    __hip_bfloat16* outh = (__hip_bfloat16*)outv;

    // --- weights -> hi(/lo) bf16 fragments, register-resident for all 512 steps ---
    bf16x8 wa[16], wal[16], wr[16], wrl[16];
    if (f32) {
        const float* WA = (const float*)Wxv + ((size_t)(p * 2048 + colg)) * 512;
        const float* WR = (const float*)Whv + ((size_t)(p * 2048 + colg)) * 512;
        #pragma unroll
        for (int kk = 0; kk < 16; ++kk) {
            split8(WA + kk * 32 + quad * 8, wa[kk], wal[kk]);
            split8(WR + kk * 32 + quad * 8, wr[kk], wrl[kk]);
        }
    } else {
        const unsigned short* WA = (const unsigned short*)Wxv + ((size_t)(p * 2048 + colg)) * 512;
        const unsigned short* WR = (const unsigned short*)Whv + ((size_t)(p * 2048 + colg)) * 512;
        union { uint4 u; bf16x8 v; } cvu;
        #pragma unroll
        for (int kk = 0; kk < 16; ++kk) {
            cvu.u = *(const uint4*)(WA + kk * 32 + quad * 8); wa[kk] = cvu.v;
            cvu.u = *(const uint4*)(WR + kk * 32 + quad * 8); wr[kk] = cvu.v;
        }
    }
    float bias;
    if (f32) bias = ((const float*)bxv)[p * 2048 + colg] + ((const float*)bhv)[p * 2048 + colg];
    else     bias = b2f(((const unsigned short*)bxv)[p * 2048 + colg])
                  + b2f(((const unsigned short*)bhv)[p * 2048 + colg]);

    // pointwise mapping: elems (b, n0), (b, n0+1); fp32 c-state in registers
    const int e0 = tid * 2;
    const int pbb = e0 >> 4;
    const int pn0 = e0 & 15;
    float cv[2];
    cv[0] = cws[p * 16384 + pbb * 512 + wt * 16 + pn0];
    cv[1] = cws[p * 16384 + pbb * 512 + wt * 16 + pn0 + 1];

    const unsigned short* xb = (const unsigned short*)xv;

    #define STAGE_X_BF16(T)                                                      \
        { _Pragma("unroll")                                                      \
          for (int j = 0; j < 8; ++j) {                                          \
              int L = j * 256 + tid;                                             \
              int rem = L & 127;                                                 \
              int row = ((rem >> 6) << 4) + (rem & 15);                          \
              int kcol = ((L >> 7) << 5) + (((rem >> 4) & 3) << 3);              \
              *(uint4*)(smem + (L << 4)) =                                       \
                  *(const uint4*)(xb + ((size_t)row * 512 + (T)) * 512 + kcol);  \
          } }

    #define STAGE_X_F32(T)                                                       \
        { _Pragma("unroll")                                                      \
          for (int j = 0; j < 8; ++j) {                                          \
              int L = j * 256 + tid;                                             \
              int rem = L & 127;                                                 \
              int row = ((rem >> 6) << 4) + (rem & 15);                          \
              int kcol = ((L >> 7) << 5) + (((rem >> 4) & 3) << 3);              \
              const float* xp = (const float*)xv + ((size_t)row * 512 + (T)) * 512 + kcol; \
              bf16x8 hi_, lo_;                                                   \
              split8(xp, hi_, lo_);                                              \
              *(bf16x8*)(smem + (L << 4)) = hi_;                                 \
              *(bf16x8*)(smem + 32768 + (L << 4)) = lo_;                         \
          } }

    // gather-then-scatter: 2 arrays (hi,lo) -> LDS regions DH/DL
    #define GATHER2(SH, SL, DH, DL)                                              \
        { u64 vH[16], vL[16];                                                    \
          _Pragma("unroll")                                                      \
          for (int j = 0; j < 8; ++j) {                                          \
              int L = j * 256 + tid;                                             \
              int rem = L & 127;                                                 \
              int row = ((rem >> 6) << 4) + (rem & 15);                          \
              int kcol = ((L >> 7) << 5) + (((rem >> 4) & 3) << 3);              \
              size_t hoff = (size_t)row * 512 + kcol;                            \
              vH[j*2] = gload8((SH) + hoff); vH[j*2+1] = gload8((SH) + hoff + 4);\
              vL[j*2] = gload8((SL) + hoff); vL[j*2+1] = gload8((SL) + hoff + 4);\
          }                                                                      \
          _Pragma("unroll")                                                      \
          for (int j = 0; j < 8; ++j) {                                          \
              int L = j * 256 + tid;                                             \
              u64* dH = (u64*)(smem + (DH) + (L << 4));                          \
              u64* dL = (u64*)(smem + (DL) + (L << 4));                          \
              dH[0] = vH[j*2]; dH[1] = vH[j*2+1];                                \
              dL[0] = vL[j*2]; dL[1] = vL[j*2+1];                                \
          } }

    // lane j polls flag of WG j; thresholds <=0 are skipped
    #define POLL(THR_E, THR_O)                                                   \
        { if (tid < 64) {                                                        \
              int thr_ = ((tid & 1) == 0) ? (THR_E) : (THR_O);                   \
              if (thr_ > 0) {                                                    \
                  while ((int)__hip_atomic_load(&flags[tid * 16],                \
                             __ATOMIC_RELAXED, __HIP_MEMORY_SCOPE_AGENT) < thr_) \
                      __builtin_amdgcn_s_sleep(1);                               \
              }                                                                  \
          }                                                                      \
          __syncthreads(); }

    // MFMA sub-phases (A tiles @0/32K, R tiles @64K/96K)
    #define MM_A_F32()                                                           \
        { _Pragma("unroll")                                                      \
          for (int kk = 0; kk < 16; ++kk) {                                      \
              bf16x8 Aha = *(const bf16x8*)(sl + kk * 2048);                     \
              bf16x8 Ahb = *(const bf16x8*)(sl + kk * 2048 + 1024);              \
              bf16x8 Ala = *(const bf16x8*)(sl + 32768 + kk * 2048);             \
              bf16x8 Alb = *(const bf16x8*)(sl + 32768 + kk * 2048 + 1024);      \
              acc0 = MFMA16(Aha, wa[kk], acc0);  acc1 = MFMA16(Ahb, wa[kk], acc1);   \
              acc0 = MFMA16(Aha, wal[kk], acc0); acc1 = MFMA16(Ahb, wal[kk], acc1);  \
              acc0 = MFMA16(Ala, wa[kk], acc0);  acc1 = MFMA16(Alb, wa[kk], acc1);   \
          } }

    #define MM_R_F32()                                                           \
        { _Pragma("unroll")                                                      \
          for (int kk = 0; kk < 16; ++kk) {                                      \
              bf16x8 Rha = *(const bf16x8*)(sl + 65536 + kk * 2048);             \
              bf16x8 Rhb = *(const bf16x8*)(sl + 65536 + kk * 2048 + 1024);      \
              bf16x8 Rla = *(const bf16x8*)(sl + 98304 + kk * 2048);             \
              bf16x8 Rlb = *(const bf16x8*)(sl + 98304 + kk * 2048 + 1024);      \
              acc0 = MFMA16(Rha, wr[kk], acc0);  acc1 = MFMA16(Rhb, wr[kk], acc1);   \
              acc0 = MFMA16(Rha, wrl[kk], acc0); acc1 = MFMA16(Rhb, wrl[kk], acc1);  \
              acc0 = MFMA16(Rla, wr[kk], acc0);  acc1 = MFMA16(Rlb, wr[kk], acc1);   \
          } }

    #define MM_A_BF16_P0()                                                       \
        { _Pragma("unroll")                                                      \
          for (int kk = 0; kk < 16; ++kk) {                                      \
              bf16x8 Aha = *(const bf16x8*)(sl + kk * 2048);                     \
              bf16x8 Ahb = *(const bf16x8*)(sl + kk * 2048 + 1024);              \
              acc0 = MFMA16(Aha, wa[kk], acc0);  acc1 = MFMA16(Ahb, wa[kk], acc1);   \
          } }

    #define MM_A_BF16_P1()                                                       \
        { _Pragma("unroll")                                                      \
          for (int kk = 0; kk < 16; ++kk) {                                      \
              bf16x8 Aha = *(const bf16x8*)(sl + kk * 2048);                     \
              bf16x8 Ahb = *(const bf16x8*)(sl + kk * 2048 + 1024);              \
              bf16x8 Ala = *(const bf16x8*)(sl + 32768 + kk * 2048);             \
              bf16x8 Alb = *(const bf16x8*)(sl + 32768 + kk * 2048 + 1024);      \
              acc0 = MFMA16(Aha, wa[kk], acc0);  acc1 = MFMA16(Ahb, wa[kk], acc1);   \
              acc0 = MFMA16(Ala, wa[kk], acc0);  acc1 = MFMA16(Alb, wa[kk], acc1);   \
          } }

    #define MM_R_BF16()                                                          \
        { _Pragma("unroll")                                                      \
          for (int kk = 0; kk < 16; ++kk) {                                      \
              bf16x8 Rha = *(const bf16x8*)(sl + 65536 + kk * 2048);             \
              bf16x8 Rhb = *(const bf16x8*)(sl + 65536 + kk * 2048 + 1024);      \
              bf16x8 Rla = *(const bf16x8*)(sl + 98304 + kk * 2048);             \
              bf16x8 Rlb = *(const bf16x8*)(sl + 98304 + kk * 2048 + 1024);      \
              acc0 = MFMA16(Rha, wr[kk], acc0);  acc1 = MFMA16(Rhb, wr[kk], acc1);   \
              acc0 = MFMA16(Rla, wr[kk], acc0);  acc1 = MFMA16(Rlb, wr[kk], acc1);   \
          } }

    // pre-stage x(0) for layer 0
    if (p == 0) {
        if (f32) { STAGE_X_F32(0) } else { STAGE_X_BF16(0) }
        __syncthreads();
    }

    for (int k = 0; k <= 512; ++k) {
        const bool doComp = (p == 0) ? (k < 512) : (k > 0);
        if (!doComp) {
            // p==1 at k==0, p==0 at k==512: just advance our flag
            if (tid == 0)
                __hip_atomic_store(&flags[blockIdx.x * 16], (unsigned)(k + 1),
                                   __ATOMIC_RELAXED, __HIP_MEMORY_SCOPE_AGENT);
            continue;
        }

        const char* sl = smem + (lane << 4);
        f32x4 acc0 = {bias, bias, bias, bias};
        f32x4 acc1 = {bias, bias, bias, bias};
        const int t = (p == 0) ? k : (k - 1);

        if (p == 0) {
            // ---- A-GEMM first (x tile prefetched; no peer dependency) ----
            if (f32) { MM_A_F32() } else { MM_A_BF16_P0() }
            // ---- wait: p0 peers >= k (data), p1 >= k-2 (slot-reuse flow control) ----
            POLL(k, k - 2)
            // ---- gather R = h0[k-1] (ring slot k&3) ----
            {
                const __hip_bfloat16* Rhi = h0hi + (size_t)(k & 3) * 16384;
                const __hip_bfloat16* Rlo = h0lo + (size_t)(k & 3) * 16384;
                GATHER2(Rhi, Rlo, 65536, 98304)
            }
            __syncthreads();
            if (f32) { MM_R_F32() } else { MM_R_BF16() }
        } else {
            // ---- A = h0[k-1] (ring slot k&3); p0 runs ahead so this is usually free ----
            POLL(k, 0)
            {
                const __hip_bfloat16* Ahi = h0hi + (size_t)(k & 3) * 16384;
                const __hip_bfloat16* Alo = h0lo + (size_t)(k & 3) * 16384;
                GATHER2(Ahi, Alo, 0, 32768)
            }
            __syncthreads();
            if (f32) { MM_A_F32() } else { MM_A_BF16_P1() }
            // ---- now wait for own-layer peers, then R = h1[k-2] (parity (k+1)&1) ----
            POLL(0, k)
            {
                const __hip_bfloat16* Rhi = h1hi + (size_t)((k + 1) & 1) * 16384;
                const __hip_bfloat16* Rlo = h1lo + (size_t)((k + 1) & 1) * 16384;
                GATHER2(Rhi, Rlo, 65536, 98304)
            }
            __syncthreads();
            if (f32) { MM_R_F32() } else { MM_R_BF16() }
        }

        // ---- gate transpose via gbuf ----
        #pragma unroll
        for (int r = 0; r < 4; ++r) {
            gbuf[(q * 32 + quad * 4 + r) * 17 + n16]      = acc0[r];
            gbuf[(q * 32 + 16 + quad * 4 + r) * 17 + n16] = acc1[r];
        }
        __syncthreads();

        // ---- pointwise epilogue ----
        __hip_bfloat16* Ohi = (p == 0) ? h0hi + (size_t)((k + 1) & 3) * 16384
                                       : h1hi + (size_t)(k & 1) * 16384;
        __hip_bfloat16* Olo = (p == 0) ? h0lo + (size_t)((k + 1) & 3) * 16384
                                       : h1lo + (size_t)(k & 1) * 16384;
        float rh[2], rc[2];
        #pragma unroll
        for (int j = 0; j < 2; ++j) {
            int n = pn0 + j;
            float ig = gbuf[(0 * 32 + pbb) * 17 + n];
            float fg = gbuf[(1 * 32 + pbb) * 17 + n];
            float gg = gbuf[(2 * 32 + pbb) * 17 + n];
            float og = gbuf[(3 * 32 + pbb) * 17 + n];
            float cnew = sigf(fg) * cv[j] + sigf(ig) * tanhf(gg);
            cv[j] = cnew; rc[j] = cnew;
            rh[j] = sigf(og) * tanhf(cnew);
        }
        unsigned phi = 0, plo = 0, pcn = 0;
        #pragma unroll
        for (int j = 0; j < 2; ++j) {
            unsigned short hu = f2u(rh[j]);
            unsigned short lu = f2u(rh[j] - b2f(hu));
            phi |= ((unsigned)hu) << (16 * j);
            plo |= ((unsigned)lu) << (16 * j);
            pcn |= ((unsigned)f2u(rc[j])) << (16 * j);
        }
        const int idx = pbb * 512 + wt * 16 + pn0;
        gstore4(Ohi + idx, phi);
        gstore4(Olo + idx, plo);

        // ---- publish ASAP: drain h stores, then flag; defer out stores ----
        __syncthreads();
        if (tid == 0)
            __hip_atomic_store(&flags[blockIdx.x * 16], (unsigned)(k + 1),
                               __ATOMIC_RELAXED, __HIP_MEMORY_SCOPE_AGENT);

        if (p == 1) {
            size_t oidx = ((size_t)pbb * 512 + t) * 512 + wt * 16 + pn0;
            if (f32) { outf[oidx] = rh[0]; outf[oidx + 1] = rh[1]; }
            else     { *(unsigned*)(outh + oidx) = phi; }
            if (k == 512) {
                if (f32) {
                    outf[HN_OFF + 16384 + idx] = rh[0]; outf[HN_OFF + 16385 + idx] = rh[1];
                    outf[CN_OFF + 16384 + idx] = rc[0]; outf[CN_OFF + 16385 + idx] = rc[1];
                } else {
                    *(unsigned*)(outh + HN_OFF + 16384 + idx) = phi;
                    *(unsigned*)(outh + CN_OFF + 16384 + idx) = pcn;
                }
            }
        } else if (k == 511) {
            if (f32) {
                outf[HN_OFF + idx] = rh[0]; outf[HN_OFF + idx + 1] = rh[1];
                outf[CN_OFF + idx] = rc[0]; outf[CN_OFF + idx + 1] = rc[1];
            } else {
                *(unsigned*)(outh + HN_OFF + idx) = phi;
                *(unsigned*)(outh + CN_OFF + idx) = pcn;
            }
        }

        // ---- prefetch next x tile into A region (overlaps peers' lag) ----
        if (p == 0) {
            if (k + 1 < 512) {
                if (f32) { STAGE_X_F32(k + 1) } else { STAGE_X_BF16(k + 1) }
            }
            __syncthreads();
        }
    }

    // first finishing layer-1 WG releases the ballast
    if (blockIdx.x == 1 && tid == 0)
        __hip_atomic_store(&flags[8], 1u, __ATOMIC_RELAXED, __HIP_MEMORY_SCOPE_AGENT);
}

extern "C" void kernel_launch(void* const* d_in, const int* in_sizes, int n_in,
                              void* d_out, int out_size, void* d_ws, size_t ws_size,
                              hipStream_t stream)
{
    const void* x  = d_in[0];
    const void* h0 = d_in[1];
    const void* c0 = d_in[2];
    const void* Wx = d_in[3];
    const void* bx = d_in[4];
    const void* Wh = d_in[5];
    const void* bh = d_in[6];

    char* ws = (char*)d_ws;                                    // total need: ~529 KB
    __hip_bfloat16* h0hi = (__hip_bfloat16*)(ws);              // [4][16384] bf16 (ring)
    __hip_bfloat16* h0lo = (__hip_bfloat16*)(ws + 131072);     // [4][16384]
    __hip_bfloat16* h1hi = (__hip_bfloat16*)(ws + 262144);     // [2][16384]
    __hip_bfloat16* h1lo = (__hip_bfloat16*)(ws + 327680);     // [2][16384]
    float*          cws  = (float*)(ws + 393216);              // [2][16384] f32
    unsigned*       flags = (unsigned*)(ws + 524288);          // 64 slots x 16 words
    unsigned*       dflag = (unsigned*)(ws + 528384);

    lstm_detect<<<1, 256, 0, stream>>>((const unsigned*)Wx, dflag, flags);
    lstm_init<<<64, 256, 0, stream>>>(h0, c0, h0hi, h0lo, h1hi, h1lo, cws, dflag);
    lstm_seq<<<256, 256, 0, stream>>>(x, Wx, bx, Wh, bh,
                                      h0hi, h0lo, h1hi, h1lo, cws, flags, dflag, d_out);
}